// Round 1
// baseline (35.085 us; speedup 1.0000x reference)
//
#include <hip/hip_runtime.h>
#include <math.h>

// Problem constants (from reference): B=4, T=4096, H=2048, K=4, FB=H/2=1024
#define HDIM 2048
#define FB   1024
#define NK   4
#define NTOK 16384   // B*T

// ---------------------------------------------------------------------------
// Kernel 1: effective weights  e[k][n] = sum_f w[k][f] * cos(2*pi*f*n/HDIM)
// This folds the rfft-real-part + spectral projection into a single (K,H)
// matrix, turning the FFT into a plain dot product per token.
// 512 blocks x 256 threads: 16 lanes cooperate per output, 64 cosf each.
// Integer phase p = (f*n) mod 2048 keeps cosf args in [0, 2*pi) (exact).
// ---------------------------------------------------------------------------
__global__ __launch_bounds__(256) void build_eff(const float* __restrict__ w,
                                                 float* __restrict__ e) {
    int gid = blockIdx.x * 256 + threadIdx.x;
    int oid = gid >> 4;        // output id 0..8191
    int sub = gid & 15;        // sub-lane within 16-group
    int k = oid >> 11;         // 0..3
    int n = oid & 2047;        // 0..2047
    const float* wk = w + k * FB;

    const float c = 6.283185307179586f / 2048.0f;
    int step = (n << 4) & 2047;     // phase increment per j (f += 16)
    int p = (n * sub) & 2047;       // phase for f = sub
    float acc = 0.0f;
#pragma unroll 8
    for (int j = 0; j < 64; ++j) {
        int f = (j << 4) + sub;
        acc = fmaf(wk[f], cosf((float)p * c), acc);
        p = (p + step) & 2047;
    }
    // reduce across the 16-lane group
    acc += __shfl_xor(acc, 1);
    acc += __shfl_xor(acc, 2);
    acc += __shfl_xor(acc, 4);
    acc += __shfl_xor(acc, 8);
    if (sub == 0) e[oid] = acc;
}

// ---------------------------------------------------------------------------
// Kernel 2: streaming pass over x. Per token: L2 energy + 4 dots with e,
// then gate / blend / tanh. One wave per 4 tokens, e staged in LDS (32 KB).
// Grid: NTOK/16 = 1024 blocks x 256 threads (4 waves, 4 tokens each).
// ---------------------------------------------------------------------------
__global__ __launch_bounds__(256) void spectral_main(
    const float* __restrict__ x,
    const float* __restrict__ e,
    const float* __restrict__ thr,
    const float* __restrict__ blend,
    float* __restrict__ out) {
    __shared__ float4 els[NK * HDIM / 4];   // [k*512 + n4] : 2048 float4 = 32 KB

    int tid = threadIdx.x;
    const float4* eg = (const float4*)e;
#pragma unroll
    for (int i = 0; i < 8; ++i) els[i * 256 + tid] = eg[i * 256 + tid];
    __syncthreads();

    // uniform small params (L1-cached)
    float th0 = fabsf(thr[0]), th1 = fabsf(thr[1]);
    float th2 = fabsf(thr[2]), th3 = fabsf(thr[3]);
    float b0 = blend[0], b1 = blend[1], b2 = blend[2], b3 = blend[3];

    int wave = tid >> 6;
    int lane = tid & 63;
    int tokbase = blockIdx.x * 16 + wave * 4;

    for (int i = 0; i < 4; ++i) {
        int tok = tokbase + i;
        const float4* xr = (const float4*)(x + (size_t)tok * HDIM);
        float en = 0.0f, a0 = 0.0f, a1 = 0.0f, a2 = 0.0f, a3 = 0.0f;
#pragma unroll
        for (int cच = 0; cच < 8; ++cच) {
            int idx = cच * 64 + lane;
            float4 xv = xr[idx];
            float4 e0 = els[0 * 512 + idx];
            float4 e1 = els[1 * 512 + idx];
            float4 e2 = els[2 * 512 + idx];
            float4 e3 = els[3 * 512 + idx];
            en = fmaf(xv.x, xv.x, fmaf(xv.y, xv.y, fmaf(xv.z, xv.z, fmaf(xv.w, xv.w, en))));
            a0 = fmaf(xv.x, e0.x, fmaf(xv.y, e0.y, fmaf(xv.z, e0.z, fmaf(xv.w, e0.w, a0))));
            a1 = fmaf(xv.x, e1.x, fmaf(xv.y, e1.y, fmaf(xv.z, e1.z, fmaf(xv.w, e1.w, a1))));
            a2 = fmaf(xv.x, e2.x, fmaf(xv.y, e2.y, fmaf(xv.z, e2.z, fmaf(xv.w, e2.w, a2))));
            a3 = fmaf(xv.x, e3.x, fmaf(xv.y, e3.y, fmaf(xv.z, e3.z, fmaf(xv.w, e3.w, a3))));
        }
        // 64-lane butterfly reduction of the 5 accumulators
#pragma unroll
        for (int s = 1; s < 64; s <<= 1) {
            en += __shfl_xor(en, s);
            a0 += __shfl_xor(a0, s);
            a1 += __shfl_xor(a1, s);
            a2 += __shfl_xor(a2, s);
            a3 += __shfl_xor(a3, s);
        }
        if (lane == 0) {
            float energy = sqrtf(en);
            float z = 0.0f;
            if (energy > th0) z = fmaf(b0, a0, z);
            if (energy > th1) z = fmaf(b1, a1, z);
            if (energy > th2) z = fmaf(b2, a2, z);
            if (energy > th3) z = fmaf(b3, a3, z);
            out[tok] = tanhf(z);
        }
    }
}

extern "C" void kernel_launch(void* const* d_in, const int* in_sizes, int n_in,
                              void* d_out, int out_size, void* d_ws, size_t ws_size,
                              hipStream_t stream) {
    const float* x     = (const float*)d_in[0];  // (B,T,H) f32
    const float* w     = (const float*)d_in[1];  // (K,FB)  f32
    const float* thr   = (const float*)d_in[2];  // (K,)    f32
    const float* blend = (const float*)d_in[3];  // (1,K)   f32
    float* out = (float*)d_out;                  // (B,T,1) f32
    float* e   = (float*)d_ws;                   // K*HDIM f32 = 32 KB scratch

    build_eff<<<512, 256, 0, stream>>>(w, e);
    spectral_main<<<NTOK / 16, 256, 0, stream>>>(x, e, thr, blend, out);
}

// Round 2
// 34.696 us; speedup vs baseline: 1.0112x; 1.0112x over previous
//
#include <hip/hip_runtime.h>
#include <math.h>

// Problem constants (from reference): B=4, T=4096, H=2048, K=4, FB=H/2=1024
#define HDIM 2048
#define FB   1024
#define NK   4
#define NTOK 16384   // B*T

// ---------------------------------------------------------------------------
// Kernel 1: effective weights  e[k][n] = sum_f w[k][f] * cos(2*pi*f*n/HDIM)
// Folds rfft-real + spectral projection into one (K,H) matrix.
// Integer phase p = (f*n) mod 2048 -> revolutions p/2048 in [0,1):
// v_cos_f32 (__builtin_amdgcn_cosf) takes REVOLUTIONS, so no range
// reduction is needed at all (vs libm cosf's ~30-instr Payne-Hanek).
// 512 blocks x 256 threads: 16 lanes cooperate per output, 64 cos each.
// ---------------------------------------------------------------------------
__global__ __launch_bounds__(256) void build_eff(const float* __restrict__ w,
                                                 float* __restrict__ e) {
    int gid = blockIdx.x * 256 + threadIdx.x;
    int oid = gid >> 4;        // output id 0..8191
    int sub = gid & 15;        // sub-lane within 16-group
    int k = oid >> 11;         // 0..3
    int n = oid & 2047;        // 0..2047
    const float* wk = w + k * FB;

    const float inv = 1.0f / 2048.0f;   // phase -> revolutions
    int step = (n << 4) & 2047;         // phase increment per j (f += 16)
    int p = (n * sub) & 2047;           // phase for f = sub
    float acc = 0.0f;
#pragma unroll 8
    for (int j = 0; j < 64; ++j) {
        int f = (j << 4) + sub;
        acc = fmaf(wk[f], __builtin_amdgcn_cosf((float)p * inv), acc);
        p = (p + step) & 2047;
    }
    // reduce across the 16-lane group
    acc += __shfl_xor(acc, 1);
    acc += __shfl_xor(acc, 2);
    acc += __shfl_xor(acc, 4);
    acc += __shfl_xor(acc, 8);
    if (sub == 0) e[oid] = acc;
}

// ---------------------------------------------------------------------------
// epilogue helper: gate / blend / tanh for one token (fully inlined,
// compile-time indices only -> stays in registers)
// ---------------------------------------------------------------------------
__device__ __forceinline__ float finish_tok(float en, const float* a,
                                            const float* th, const float* bl) {
    float energy = sqrtf(en);
    float z = 0.0f;
#pragma unroll
    for (int k = 0; k < NK; ++k)
        if (energy > th[k]) z = fmaf(bl[k], a[k], z);
    return tanhf(z);
}

// ---------------------------------------------------------------------------
// Kernel 2: streaming pass over x. Each wave owns 4 consecutive tokens and
// processes them in ONE fused chunk loop so each e-float4 LDS read is shared
// by 4 tokens (LDS traffic /4 vs per-token loops) and all 32 global loads
// are independent (deep vmcnt queue).
// Grid: NTOK/16 = 1024 blocks x 256 threads (4 waves x 4 tokens).
// ---------------------------------------------------------------------------
__global__ __launch_bounds__(256) void spectral_main(
    const float* __restrict__ x,
    const float* __restrict__ e,
    const float* __restrict__ thr,
    const float* __restrict__ blend,
    float* __restrict__ out) {
    __shared__ float4 els[NK * HDIM / 4];   // [k*512 + n4] : 2048 float4 = 32 KB

    int tid = threadIdx.x;
    const float4* eg = (const float4*)e;
#pragma unroll
    for (int i = 0; i < 8; ++i) els[i * 256 + tid] = eg[i * 256 + tid];
    __syncthreads();

    float th[NK], bl[NK];
#pragma unroll
    for (int k = 0; k < NK; ++k) { th[k] = fabsf(thr[k]); bl[k] = blend[k]; }

    int wave = tid >> 6;
    int lane = tid & 63;
    int tok0 = blockIdx.x * 16 + wave * 4;
    const float4* xr = (const float4*)x + (size_t)tok0 * (HDIM / 4);

    float en[4] = {0.f, 0.f, 0.f, 0.f};
    float ac[4][NK] = {};

#pragma unroll
    for (int c = 0; c < 8; ++c) {
        int idx = c * 64 + lane;
        float4 ev[NK];
#pragma unroll
        for (int k = 0; k < NK; ++k) ev[k] = els[k * 512 + idx];
        float4 xv[4];
#pragma unroll
        for (int t = 0; t < 4; ++t) xv[t] = xr[t * 512 + idx];
#pragma unroll
        for (int t = 0; t < 4; ++t) {
            float4 v = xv[t];
            en[t] = fmaf(v.x, v.x, fmaf(v.y, v.y, fmaf(v.z, v.z, fmaf(v.w, v.w, en[t]))));
#pragma unroll
            for (int k = 0; k < NK; ++k) {
                float4 w4 = ev[k];
                ac[t][k] = fmaf(v.x, w4.x, fmaf(v.y, w4.y,
                           fmaf(v.z, w4.z, fmaf(v.w, w4.w, ac[t][k]))));
            }
        }
    }

    // 64-lane butterfly reduction of the 20 accumulators
#pragma unroll
    for (int s = 1; s < 64; s <<= 1) {
#pragma unroll
        for (int t = 0; t < 4; ++t) {
            en[t] += __shfl_xor(en[t], s);
#pragma unroll
            for (int k = 0; k < NK; ++k) ac[t][k] += __shfl_xor(ac[t][k], s);
        }
    }

    if (lane == 0) {
        float4 o;
        o.x = finish_tok(en[0], ac[0], th, bl);
        o.y = finish_tok(en[1], ac[1], th, bl);
        o.z = finish_tok(en[2], ac[2], th, bl);
        o.w = finish_tok(en[3], ac[3], th, bl);
        *(float4*)(out + tok0) = o;   // tok0 % 4 == 0 -> 16B aligned
    }
}

extern "C" void kernel_launch(void* const* d_in, const int* in_sizes, int n_in,
                              void* d_out, int out_size, void* d_ws, size_t ws_size,
                              hipStream_t stream) {
    const float* x     = (const float*)d_in[0];  // (B,T,H) f32
    const float* w     = (const float*)d_in[1];  // (K,FB)  f32
    const float* thr   = (const float*)d_in[2];  // (K,)    f32
    const float* blend = (const float*)d_in[3];  // (1,K)   f32
    float* out = (float*)d_out;                  // (B,T,1) f32
    float* e   = (float*)d_ws;                   // K*HDIM f32 = 32 KB scratch

    build_eff<<<512, 256, 0, stream>>>(w, e);
    spectral_main<<<NTOK / 16, 256, 0, stream>>>(x, e, thr, blend, out);
}

// Round 4
// 32.954 us; speedup vs baseline: 1.0646x; 1.0528x over previous
//
#include <hip/hip_runtime.h>
#include <math.h>

// Problem constants (from reference): B=4, T=4096, H=2048, K=4, FB=H/2=1024
#define HDIM 2048
#define FB   1024
#define NK   4
#define NTOK 16384   // B*T

// clang ext vector: accepted by __builtin_nontemporal_load (HIP float4 is not)
typedef float f32x4 __attribute__((ext_vector_type(4)));

// ---------------------------------------------------------------------------
// Kernel 1: effective weights  e[k][n] = sum_f w[k][f] * cos(2*pi*f*n/HDIM)
// Folds rfft-real + spectral projection into one (K,H) matrix.
// Integer phase p = (f*n) mod 2048 -> revolutions p/2048 in [0,1):
// v_cos_f32 (__builtin_amdgcn_cosf) takes REVOLUTIONS, so no range
// reduction needed (verified round 2: absmax 1.2e-4).
// ---------------------------------------------------------------------------
__global__ __launch_bounds__(256) void build_eff(const float* __restrict__ w,
                                                 float* __restrict__ e) {
    int gid = blockIdx.x * 256 + threadIdx.x;
    int oid = gid >> 4;        // output id 0..8191
    int sub = gid & 15;        // sub-lane within 16-group
    int k = oid >> 11;         // 0..3
    int n = oid & 2047;        // 0..2047
    const float* wk = w + k * FB;

    const float inv = 1.0f / 2048.0f;   // phase -> revolutions
    int step = (n << 4) & 2047;         // phase increment per j (f += 16)
    int p = (n * sub) & 2047;           // phase for f = sub
    float acc = 0.0f;
#pragma unroll 8
    for (int j = 0; j < 64; ++j) {
        int f = (j << 4) + sub;
        acc = fmaf(wk[f], __builtin_amdgcn_cosf((float)p * inv), acc);
        p = (p + step) & 2047;
    }
    acc += __shfl_xor(acc, 1);
    acc += __shfl_xor(acc, 2);
    acc += __shfl_xor(acc, 4);
    acc += __shfl_xor(acc, 8);
    if (sub == 0) e[oid] = acc;
}

// ---------------------------------------------------------------------------
// epilogue helper: gate / blend / tanh for one token (compile-time indices
// only after full unroll -> stays in registers)
// ---------------------------------------------------------------------------
__device__ __forceinline__ float finish_tok(float en, const float* a,
                                            const float* th, const float* bl) {
    float energy = sqrtf(en);
    float z = 0.0f;
#pragma unroll
    for (int k = 0; k < NK; ++k)
        if (energy > th[k]) z = fmaf(bl[k], a[k], z);
    return tanhf(z);
}

// ---------------------------------------------------------------------------
// Kernel 2: streaming pass over x. Each wave owns 4 consecutive tokens in one
// fused chunk loop (e LDS reads shared x4). This round:
//   - __launch_bounds__(256,4): pin VGPR<=128 so LDS-allowed 4 blocks/CU
//     (16 waves/CU) is realized.
//   - chunks 0-1 of x prefetched (nontemporal) BEFORE e-staging + barrier,
//     so first HBM latency overlaps staging + barrier drain.
//   - nontemporal loads for all x traffic (stream-once, no cache alloc).
// Grid: NTOK/16 = 1024 blocks x 256 threads (4 waves x 4 tokens).
// ---------------------------------------------------------------------------
__global__ __launch_bounds__(256, 4) void spectral_main(
    const float* __restrict__ x,
    const float* __restrict__ e,
    const float* __restrict__ thr,
    const float* __restrict__ blend,
    float* __restrict__ out) {
    __shared__ f32x4 els[NK * HDIM / 4];   // 2048 float4 = 32 KB

    int tid = threadIdx.x;
    int wave = tid >> 6;
    int lane = tid & 63;
    int tok0 = blockIdx.x * 16 + wave * 4;
    const f32x4* xr = (const f32x4*)x + (size_t)tok0 * (HDIM / 4);

    // --- prefetch chunks 0,1 for all 4 tokens (8 x 1KB/wave in flight) ---
    f32x4 xv0[4], xv1[4];
#pragma unroll
    for (int t = 0; t < 4; ++t) {
        xv0[t] = __builtin_nontemporal_load(&xr[t * 512 + 0 * 64 + lane]);
        xv1[t] = __builtin_nontemporal_load(&xr[t * 512 + 1 * 64 + lane]);
    }

    // --- stage e into LDS (L2-hot after build_eff) ---
    const f32x4* eg = (const f32x4*)e;
#pragma unroll
    for (int i = 0; i < 8; ++i) els[i * 256 + tid] = eg[i * 256 + tid];

    float th[NK], bl[NK];
#pragma unroll
    for (int k = 0; k < NK; ++k) { th[k] = fabsf(thr[k]); bl[k] = blend[k]; }

    __syncthreads();

    float en[4] = {0.f, 0.f, 0.f, 0.f};
    float ac[4][NK] = {};

#pragma unroll
    for (int c = 0; c < 8; ++c) {
        int idx = c * 64 + lane;
        f32x4 ev[NK];
#pragma unroll
        for (int k = 0; k < NK; ++k) ev[k] = els[k * 512 + idx];
        f32x4 xv[4];
        if (c == 0) {
#pragma unroll
            for (int t = 0; t < 4; ++t) xv[t] = xv0[t];
        } else if (c == 1) {
#pragma unroll
            for (int t = 0; t < 4; ++t) xv[t] = xv1[t];
        } else {
#pragma unroll
            for (int t = 0; t < 4; ++t)
                xv[t] = __builtin_nontemporal_load(&xr[t * 512 + idx]);
        }
#pragma unroll
        for (int t = 0; t < 4; ++t) {
            f32x4 v = xv[t];
            en[t] = fmaf(v.x, v.x, fmaf(v.y, v.y, fmaf(v.z, v.z, fmaf(v.w, v.w, en[t]))));
#pragma unroll
            for (int k = 0; k < NK; ++k) {
                f32x4 w4 = ev[k];
                ac[t][k] = fmaf(v.x, w4.x, fmaf(v.y, w4.y,
                           fmaf(v.z, w4.z, fmaf(v.w, w4.w, ac[t][k]))));
            }
        }
    }

    // 64-lane butterfly reduction of the 20 accumulators
#pragma unroll
    for (int s = 1; s < 64; s <<= 1) {
#pragma unroll
        for (int t = 0; t < 4; ++t) {
            en[t] += __shfl_xor(en[t], s);
#pragma unroll
            for (int k = 0; k < NK; ++k) ac[t][k] += __shfl_xor(ac[t][k], s);
        }
    }

    if (lane == 0) {
        f32x4 o;
        o.x = finish_tok(en[0], ac[0], th, bl);
        o.y = finish_tok(en[1], ac[1], th, bl);
        o.z = finish_tok(en[2], ac[2], th, bl);
        o.w = finish_tok(en[3], ac[3], th, bl);
        *(f32x4*)(out + tok0) = o;   // tok0 % 4 == 0 -> 16B aligned
    }
}

extern "C" void kernel_launch(void* const* d_in, const int* in_sizes, int n_in,
                              void* d_out, int out_size, void* d_ws, size_t ws_size,
                              hipStream_t stream) {
    const float* x     = (const float*)d_in[0];  // (B,T,H) f32
    const float* w     = (const float*)d_in[1];  // (K,FB)  f32
    const float* thr   = (const float*)d_in[2];  // (K,)    f32
    const float* blend = (const float*)d_in[3];  // (1,K)   f32
    float* out = (float*)d_out;                  // (B,T,1) f32
    float* e   = (float*)d_ws;                   // K*HDIM f32 = 32 KB scratch

    build_eff<<<512, 256, 0, stream>>>(w, e);
    spectral_main<<<NTOK / 16, 256, 0, stream>>>(x, e, thr, blend, out);
}